// Round 5
// baseline (345.036 us; speedup 1.0000x reference)
//
#include <hip/hip_runtime.h>

#define T_TOK 4096
#define D_DIM 1024
#define E_EXP 8
#define H_DIM 2048
#define CAP   9216   // 8192 slots + 8*128 tile padding
#define TILES_M 72   // CAP/128

typedef __attribute__((ext_vector_type(8))) short bf16x8;
typedef __attribute__((ext_vector_type(4))) float f32x4;

__device__ inline unsigned short f2bf(float f) {
    unsigned int u = __float_as_uint(f);
    unsigned int r = (u + 0x7fffu + ((u >> 16) & 1u)) >> 16;
    return (unsigned short)r;
}

#define GLD_LDS16(g, l)                                                        \
    __builtin_amdgcn_global_load_lds(                                          \
        (const __attribute__((address_space(1))) void*)(g),                    \
        (__attribute__((address_space(3))) void*)(l), 16, 0, 0)

// ------------- fp32 (R,C) -> bf16 transposed (C,R), per expert -------------
__global__ __launch_bounds__(256) void tcvt_kernel(const float* __restrict__ src,
                                                   unsigned short* __restrict__ dst,
                                                   int R, int C) {
    __shared__ float tile[64][65];
    size_t eo = (size_t)blockIdx.z * R * C;
    src += eo; dst += eo;
    int tx = threadIdx.x & 15, ty = threadIdx.x >> 4;
    int c0 = blockIdx.x * 64, r0 = blockIdx.y * 64;
    #pragma unroll
    for (int i = 0; i < 4; i++) {
        int row = ty + i * 16;
        float4 v = *(const float4*)&src[(size_t)(r0 + row) * C + c0 + tx * 4];
        tile[row][tx * 4 + 0] = v.x;
        tile[row][tx * 4 + 1] = v.y;
        tile[row][tx * 4 + 2] = v.z;
        tile[row][tx * 4 + 3] = v.w;
    }
    __syncthreads();
    #pragma unroll
    for (int i = 0; i < 4; i++) {
        int cc = ty + i * 16;
        int rr = tx * 4;
        ushort4 o;
        o.x = f2bf(tile[rr + 0][cc]);
        o.y = f2bf(tile[rr + 1][cc]);
        o.z = f2bf(tile[rr + 2][cc]);
        o.w = f2bf(tile[rr + 3][cc]);
        *(ushort4*)&dst[(size_t)(c0 + cc) * R + r0 + rr] = o;
    }
}

// -------- gating: logits, top-2, softmax, entropy partials + x->bf16 --------
// Atomic-free. Also emits xb (bf16 copy of x) since x is already in flight.
__global__ __launch_bounds__(256) void gating_kernel(
    const float* __restrict__ xf, const float* __restrict__ wg,
    const float* __restrict__ bg, unsigned short* __restrict__ xb,
    int* __restrict__ tk_e, float* __restrict__ tk_g,
    float* __restrict__ ent_part)
{
    __shared__ float ents[4];
    int wave = threadIdx.x >> 6, lane = threadIdx.x & 63;
    int t = blockIdx.x * 4 + wave;
    const float* xr = xf + (size_t)t * D_DIM;
    unsigned short* xbr = xb + (size_t)t * D_DIM;
    float acc[8] = {0.f,0.f,0.f,0.f,0.f,0.f,0.f,0.f};
    for (int i = 0; i < 16; i++) {
        int d = lane + i * 64;
        float xv = xr[d];
        xbr[d] = f2bf(xv);
        const float4* wr = (const float4*)(wg + (size_t)d * 8);
        float4 w0 = wr[0], w1 = wr[1];
        acc[0] += xv * w0.x; acc[1] += xv * w0.y; acc[2] += xv * w0.z; acc[3] += xv * w0.w;
        acc[4] += xv * w1.x; acc[5] += xv * w1.y; acc[6] += xv * w1.z; acc[7] += xv * w1.w;
    }
    #pragma unroll
    for (int s = 1; s < 64; s <<= 1) {
        #pragma unroll
        for (int e = 0; e < 8; e++) acc[e] += __shfl_xor(acc[e], s, 64);
    }
    if (lane == 0) {
        float l[8];
        #pragma unroll
        for (int e = 0; e < 8; e++) l[e] = acc[e] + bg[e];
        int i0 = 0;
        #pragma unroll
        for (int e = 1; e < 8; e++) if (l[e] > l[i0]) i0 = e;
        int i1 = (i0 == 0) ? 1 : 0;
        #pragma unroll
        for (int e = 0; e < 8; e++) if (e != i0 && l[e] > l[i1]) i1 = e;
        float z  = expf(l[i1] - l[i0]);          // <= 1
        float p0 = 1.0f / (1.0f + z);
        float p1 = z / (1.0f + z);
        float ent = -(p0 * logf(fmaxf(p0, 1e-8f)) + p1 * logf(fmaxf(p1, 1e-8f)));
        ents[wave] = ent;
        tk_e[t * 2 + 0] = i0; tk_g[t * 2 + 0] = p0;
        tk_e[t * 2 + 1] = i1; tk_g[t * 2 + 1] = p1;
    }
    __syncthreads();
    if (threadIdx.x == 0)
        ent_part[blockIdx.x] = ents[0] + ents[1] + ents[2] + ents[3];
}

// ---------------- entropy: reduce 1024 block partials ----------------
__global__ __launch_bounds__(256) void ent_reduce_kernel(
    const float* __restrict__ ent_part, float* __restrict__ ent_out)
{
    __shared__ float ws_[4];
    int tid = threadIdx.x;
    float s = 0.f;
    for (int i = tid; i < T_TOK / 4; i += 256) s += ent_part[i];
    #pragma unroll
    for (int d = 1; d < 64; d <<= 1) s += __shfl_xor(s, d, 64);
    if ((tid & 63) == 0) ws_[tid >> 6] = s;
    __syncthreads();
    if (tid == 0)
        *ent_out = (ws_[0] + ws_[1] + ws_[2] + ws_[3]) * (1.0f / T_TOK);
}

// ---------------- routing: count + padded offsets + scatter, atomic-free ----------------
__global__ __launch_bounds__(1024) void route_kernel(
    const int* __restrict__ tk_e, const float* __restrict__ tk_g,
    int* __restrict__ off, int* __restrict__ slot_token,
    float* __restrict__ slot_gate, int* __restrict__ slot_of)
{
    __shared__ int wt[16][8];     // per-wave totals
    __shared__ int wx[16][8];     // per-wave exclusive prefix
    __shared__ int base[9];       // padded offsets
    __shared__ int tot[8];        // true counts

    int tid = threadIdx.x, wid = tid >> 6, lane = tid & 63;
    int i0 = tid * 8;
    int ev[8];
    *(int4*)&ev[0] = *(const int4*)&tk_e[i0];
    *(int4*)&ev[4] = *(const int4*)&tk_e[i0 + 4];

    unsigned own[4] = {0u, 0u, 0u, 0u};
    #pragma unroll
    for (int j = 0; j < 8; j++) {
        int e = ev[j];
        int reg = ((e < 4) ? 0 : 2) + (e & 1);
        own[reg] += 1u << (((e >> 1) & 1) * 16);
    }
    unsigned inc[4] = {own[0], own[1], own[2], own[3]};
    #pragma unroll
    for (int d = 1; d < 64; d <<= 1) {
        #pragma unroll
        for (int k = 0; k < 4; k++) {
            unsigned t = __shfl_up(inc[k], d, 64);
            if (lane >= d) inc[k] += t;
        }
    }
    if (lane == 63) {
        #pragma unroll
        for (int e = 0; e < 8; e++) {
            int reg = ((e < 4) ? 0 : 2) + (e & 1);
            wt[wid][e] = (inc[reg] >> (((e >> 1) & 1) * 16)) & 0xFFFF;
        }
    }
    __syncthreads();
    if (tid == 0) {
        int o = 0;
        for (int e = 0; e < 8; e++) {
            int run = 0;
            for (int w = 0; w < 16; w++) { wx[w][e] = run; run += wt[w][e]; }
            tot[e] = run;
            base[e] = o;
            off[e] = o;
            o += (run + 127) & ~127;
        }
        base[8] = o;
        off[8] = o;
    }
    __syncthreads();

    #pragma unroll
    for (int e = 0; e < 8; e++) {
        int p0 = base[e] + tot[e], p1 = base[e + 1];
        for (int i = p0 + tid; i < p1; i += 1024) slot_token[i] = -1;
    }

    unsigned run[4] = {0u, 0u, 0u, 0u};
    #pragma unroll
    for (int j = 0; j < 8; j++) {
        int e = ev[j];
        int reg = ((e < 4) ? 0 : 2) + (e & 1);
        int sh = ((e >> 1) & 1) * 16;
        int lx = (int)(((inc[reg] - own[reg]) >> sh) & 0xFFFF);
        int lr = (int)((run[reg] >> sh) & 0xFFFF);
        int slot = base[e] + wx[wid][e] + lx + lr;
        run[reg] += 1u << sh;
        int i = i0 + j;
        slot_token[slot] = i >> 1;
        slot_gate[slot] = tk_g[i];
        slot_of[i] = slot;
    }
}

// ---------------- GEMM1: Hb = relu(gather(x) @ w1t[e]^T + b1[e]) ----------------
// BK=64, XOR-swizzled LDS: stored[row][c] = global[row][c ^ (row&7)] (c = 8-short chunk).
__global__ __launch_bounds__(256) void gemm1_kernel(
    const unsigned short* __restrict__ xb, const unsigned short* __restrict__ w1t,
    const float* __restrict__ b1g, const int* __restrict__ off,
    const int* __restrict__ slot_token, unsigned short* __restrict__ Hb)
{
    __shared__ __align__(16) unsigned short As[128 * 64];
    __shared__ __align__(16) unsigned short Bs[128 * 64];

    int s0 = blockIdx.x * 128;
    if (s0 >= off[E_EXP]) return;
    int e = 0;
    while (s0 >= off[e + 1]) e++;
    int n0 = blockIdx.y * 128;

    int tid = threadIdx.x;
    int wave = tid >> 6, lane = tid & 63;
    int lrow = lane & 15, quad = lane >> 4;
    int srow = lane >> 3;                  // 0..7: row within 8-row chunk
    int scol = ((lane & 7) ^ srow) * 8;    // swizzled source chunk (shorts)

    const unsigned short* wb = w1t + (size_t)e * H_DIM * D_DIM;
    const unsigned short* ap[4];
    const unsigned short* bp[4];
    #pragma unroll
    for (int j = 0; j < 4; j++) {
        int r = 32 * j + 8 * wave + srow;
        int t = slot_token[s0 + r]; if (t < 0) t = 0;
        ap[j] = xb + (size_t)t * D_DIM + scol;
        bp[j] = wb + (size_t)(n0 + r) * D_DIM + scol;
    }

    f32x4 acc[4][4];
    #pragma unroll
    for (int mi = 0; mi < 4; mi++)
        #pragma unroll
        for (int ni = 0; ni < 4; ni++) acc[mi][ni] = (f32x4){0.f, 0.f, 0.f, 0.f};

    int wr = (wave >> 1) * 64, wc = (wave & 1) * 64;
    int sw = lrow & 7;

    for (int k0 = 0; k0 < D_DIM; k0 += 64) {
        __syncthreads();
        #pragma unroll
        for (int j = 0; j < 4; j++) {
            GLD_LDS16(ap[j] + k0, As + (32 * j + 8 * wave) * 64);
            GLD_LDS16(bp[j] + k0, Bs + (32 * j + 8 * wave) * 64);
        }
        __syncthreads();
        #pragma unroll
        for (int h = 0; h < 2; h++) {
            bf16x8 af[4], bfr[4];
            #pragma unroll
            for (int i = 0; i < 4; i++) {
                int g = ((h * 4 + quad) ^ sw) * 8;
                af[i]  = *(const bf16x8*)&As[(wr + i * 16 + lrow) * 64 + g];
                bfr[i] = *(const bf16x8*)&Bs[(wc + i * 16 + lrow) * 64 + g];
            }
            #pragma unroll
            for (int mi = 0; mi < 4; mi++)
                #pragma unroll
                for (int ni = 0; ni < 4; ni++)
                    acc[mi][ni] = __builtin_amdgcn_mfma_f32_16x16x32_bf16(
                        af[mi], bfr[ni], acc[mi][ni], 0, 0, 0);
        }
    }

    #pragma unroll
    for (int ni = 0; ni < 4; ni++) {
        int h = n0 + wc + ni * 16 + lrow;
        float bv = b1g[e * H_DIM + h];
        #pragma unroll
        for (int mi = 0; mi < 4; mi++) {
            int mrow = wr + mi * 16 + quad * 4;
            #pragma unroll
            for (int r = 0; r < 4; r++) {
                float v = fmaxf(acc[mi][ni][r] + bv, 0.0f);
                Hb[(size_t)(s0 + mrow + r) * H_DIM + h] = f2bf(v);
            }
        }
    }
}

// ---------------- GEMM2: Yb = Hb @ w2t[e]^T + b2[e] (bf16 out) ----------------
__global__ __launch_bounds__(256) void gemm2_kernel(
    const unsigned short* __restrict__ Hb, const unsigned short* __restrict__ w2t,
    const float* __restrict__ b2g, const int* __restrict__ off,
    unsigned short* __restrict__ Yb)
{
    __shared__ __align__(16) unsigned short As[128 * 64];
    __shared__ __align__(16) unsigned short Bs[128 * 64];

    int s0 = blockIdx.x * 128;
    if (s0 >= off[E_EXP]) return;
    int e = 0;
    while (s0 >= off[e + 1]) e++;
    int n0 = blockIdx.y * 128;

    int tid = threadIdx.x;
    int wave = tid >> 6, lane = tid & 63;
    int lrow = lane & 15, quad = lane >> 4;
    int srow = lane >> 3;
    int scol = ((lane & 7) ^ srow) * 8;

    const unsigned short* wb = w2t + (size_t)e * D_DIM * H_DIM;
    const unsigned short* ap[4];
    const unsigned short* bp[4];
    #pragma unroll
    for (int j = 0; j < 4; j++) {
        int r = 32 * j + 8 * wave + srow;
        ap[j] = Hb + (size_t)(s0 + r) * H_DIM + scol;
        bp[j] = wb + (size_t)(n0 + r) * H_DIM + scol;
    }

    f32x4 acc[4][4];
    #pragma unroll
    for (int mi = 0; mi < 4; mi++)
        #pragma unroll
        for (int ni = 0; ni < 4; ni++) acc[mi][ni] = (f32x4){0.f, 0.f, 0.f, 0.f};

    int wr = (wave >> 1) * 64, wc = (wave & 1) * 64;
    int sw = lrow & 7;

    for (int k0 = 0; k0 < H_DIM; k0 += 64) {
        __syncthreads();
        #pragma unroll
        for (int j = 0; j < 4; j++) {
            GLD_LDS16(ap[j] + k0, As + (32 * j + 8 * wave) * 64);
            GLD_LDS16(bp[j] + k0, Bs + (32 * j + 8 * wave) * 64);
        }
        __syncthreads();
        #pragma unroll
        for (int h = 0; h < 2; h++) {
            bf16x8 af[4], bfr[4];
            #pragma unroll
            for (int i = 0; i < 4; i++) {
                int g = ((h * 4 + quad) ^ sw) * 8;
                af[i]  = *(const bf16x8*)&As[(wr + i * 16 + lrow) * 64 + g];
                bfr[i] = *(const bf16x8*)&Bs[(wc + i * 16 + lrow) * 64 + g];
            }
            #pragma unroll
            for (int mi = 0; mi < 4; mi++)
                #pragma unroll
                for (int ni = 0; ni < 4; ni++)
                    acc[mi][ni] = __builtin_amdgcn_mfma_f32_16x16x32_bf16(
                        af[mi], bfr[ni], acc[mi][ni], 0, 0, 0);
        }
    }

    #pragma unroll
    for (int ni = 0; ni < 4; ni++) {
        int d = n0 + wc + ni * 16 + lrow;
        float bv = b2g[e * D_DIM + d];
        #pragma unroll
        for (int mi = 0; mi < 4; mi++) {
            int mrow = wr + mi * 16 + quad * 4;
            #pragma unroll
            for (int r = 0; r < 4; r++) {
                Yb[(size_t)(s0 + mrow + r) * D_DIM + d] = f2bf(acc[mi][ni][r] + bv);
            }
        }
    }
}

// ---------------- combine: out[t] = g0*Y[slot0] + g1*Y[slot1] ----------------
__global__ __launch_bounds__(256) void combine_kernel(
    const unsigned short* __restrict__ Yb, const int* __restrict__ slot_of,
    const float* __restrict__ tk_g, float* __restrict__ out)
{
    int t = blockIdx.x * 2 + (threadIdx.x >> 7);
    int j = threadIdx.x & 127;                 // 8 elements per thread
    int sA = slot_of[t * 2], sB = slot_of[t * 2 + 1];
    float gA = tk_g[t * 2], gB = tk_g[t * 2 + 1];
    uint4 va = *(const uint4*)(Yb + (size_t)sA * D_DIM + j * 8);
    uint4 vb = *(const uint4*)(Yb + (size_t)sB * D_DIM + j * 8);
    const unsigned int* pa = (const unsigned int*)&va;
    const unsigned int* pb = (const unsigned int*)&vb;
    float o[8];
    #pragma unroll
    for (int i = 0; i < 4; i++) {
        float a_lo = __uint_as_float(pa[i] << 16);
        float a_hi = __uint_as_float(pa[i] & 0xffff0000u);
        float b_lo = __uint_as_float(pb[i] << 16);
        float b_hi = __uint_as_float(pb[i] & 0xffff0000u);
        o[i * 2 + 0] = gA * a_lo + gB * b_lo;
        o[i * 2 + 1] = gA * a_hi + gB * b_hi;
    }
    float* op = out + (size_t)t * D_DIM + j * 8;
    ((float4*)op)[0] = make_float4(o[0], o[1], o[2], o[3]);
    ((float4*)op)[1] = make_float4(o[4], o[5], o[6], o[7]);
}

extern "C" void kernel_launch(void* const* d_in, const int* in_sizes, int n_in,
                              void* d_out, int out_size, void* d_ws, size_t ws_size,
                              hipStream_t stream)
{
    const float* xf = (const float*)d_in[0];
    const float* wg = (const float*)d_in[1];
    const float* bg = (const float*)d_in[2];
    const float* w1 = (const float*)d_in[3];
    const float* b1 = (const float*)d_in[4];
    const float* w2 = (const float*)d_in[5];
    const float* b2 = (const float*)d_in[6];
    float* out = (float*)d_out;

    char* p = (char*)d_ws;
    int* off    = (int*)p;                              // 16 (9 used)
    int* tk_e   = off + 16;                             // 8192
    float* tk_g = (float*)(tk_e + T_TOK * 2);           // 8192
    int* slot_token = (int*)(tk_g + T_TOK * 2);         // 9216
    float* slot_gate = (float*)(slot_token + CAP);      // 9216
    int* slot_of = (int*)(slot_gate + CAP);             // 8192
    float* ent_part = (float*)(slot_of + T_TOK * 2);    // 1024
    size_t ofs = ((size_t)((char*)(ent_part + T_TOK / 4) - p) + 255) & ~(size_t)255;
    unsigned short* xb  = (unsigned short*)(p + ofs); ofs += (size_t)T_TOK * D_DIM * 2;
    unsigned short* w1t = (unsigned short*)(p + ofs); ofs += (size_t)E_EXP * D_DIM * H_DIM * 2;
    unsigned short* w2t = (unsigned short*)(p + ofs); ofs += (size_t)E_EXP * H_DIM * D_DIM * 2;
    unsigned short* Hb  = (unsigned short*)(p + ofs); ofs += (size_t)CAP * H_DIM * 2;
    unsigned short* Yb  = w1t;   // alias: w1t is dead after gemm1

    gating_kernel<<<T_TOK / 4, 256, 0, stream>>>(xf, wg, bg, xb, tk_e, tk_g, ent_part);
    ent_reduce_kernel<<<1, 256, 0, stream>>>(ent_part, out + (size_t)T_TOK * D_DIM);
    route_kernel<<<1, 1024, 0, stream>>>(tk_e, tk_g, off, slot_token, slot_gate, slot_of);
    // w1 (E, D, H) -> w1t (E, H, D)
    tcvt_kernel<<<dim3(H_DIM / 64, D_DIM / 64, E_EXP), 256, 0, stream>>>(w1, w1t, D_DIM, H_DIM);
    // w2 (E, H, D) -> w2t (E, D, H)
    tcvt_kernel<<<dim3(D_DIM / 64, H_DIM / 64, E_EXP), 256, 0, stream>>>(w2, w2t, H_DIM, D_DIM);
    gemm1_kernel<<<dim3(TILES_M, H_DIM / 128), 256, 0, stream>>>(xb, w1t, b1, off,
                                                                 slot_token, Hb);
    gemm2_kernel<<<dim3(TILES_M, D_DIM / 128), 256, 0, stream>>>(Hb, w2t, b2, off, Yb);
    combine_kernel<<<T_TOK / 2, 256, 0, stream>>>(Yb, slot_of, tk_g, out);
}

// Round 6
// 329.478 us; speedup vs baseline: 1.0472x; 1.0472x over previous
//
#include <hip/hip_runtime.h>

#define T_TOK 4096
#define D_DIM 1024
#define E_EXP 8
#define H_DIM 2048
#define CAP   9216   // 8192 slots + 8*128 tile padding
#define TILES_M 72   // CAP/128

typedef __attribute__((ext_vector_type(8))) short bf16x8;
typedef __attribute__((ext_vector_type(4))) float f32x4;

__device__ inline unsigned short f2bf(float f) {
    unsigned int u = __float_as_uint(f);
    unsigned int r = (u + 0x7fffu + ((u >> 16) & 1u)) >> 16;
    return (unsigned short)r;
}

#define GLD_LDS16(g, l)                                                        \
    __builtin_amdgcn_global_load_lds(                                          \
        (const __attribute__((address_space(1))) void*)(g),                    \
        (__attribute__((address_space(3))) void*)(l), 16, 0, 0)

// ------------- fp32 (R,C) -> bf16 transposed (C,R), per expert -------------
__global__ __launch_bounds__(256) void tcvt_kernel(const float* __restrict__ src,
                                                   unsigned short* __restrict__ dst,
                                                   int R, int C) {
    __shared__ float tile[64][65];
    size_t eo = (size_t)blockIdx.z * R * C;
    src += eo; dst += eo;
    int tx = threadIdx.x & 15, ty = threadIdx.x >> 4;
    int c0 = blockIdx.x * 64, r0 = blockIdx.y * 64;
    #pragma unroll
    for (int i = 0; i < 4; i++) {
        int row = ty + i * 16;
        float4 v = *(const float4*)&src[(size_t)(r0 + row) * C + c0 + tx * 4];
        tile[row][tx * 4 + 0] = v.x;
        tile[row][tx * 4 + 1] = v.y;
        tile[row][tx * 4 + 2] = v.z;
        tile[row][tx * 4 + 3] = v.w;
    }
    __syncthreads();
    #pragma unroll
    for (int i = 0; i < 4; i++) {
        int cc = ty + i * 16;
        int rr = tx * 4;
        ushort4 o;
        o.x = f2bf(tile[rr + 0][cc]);
        o.y = f2bf(tile[rr + 1][cc]);
        o.z = f2bf(tile[rr + 2][cc]);
        o.w = f2bf(tile[rr + 3][cc]);
        *(ushort4*)&dst[(size_t)(c0 + cc) * R + r0 + rr] = o;
    }
}

// -------- gating: logits, top-2, softmax, entropy partials + x->bf16 --------
__global__ __launch_bounds__(256) void gating_kernel(
    const float* __restrict__ xf, const float* __restrict__ wg,
    const float* __restrict__ bg, unsigned short* __restrict__ xb,
    int* __restrict__ tk_e, float* __restrict__ tk_g,
    float* __restrict__ ent_part)
{
    __shared__ float ents[4];
    int wave = threadIdx.x >> 6, lane = threadIdx.x & 63;
    int t = blockIdx.x * 4 + wave;
    const float* xr = xf + (size_t)t * D_DIM;
    unsigned short* xbr = xb + (size_t)t * D_DIM;
    float acc[8] = {0.f,0.f,0.f,0.f,0.f,0.f,0.f,0.f};
    for (int i = 0; i < 16; i++) {
        int d = lane + i * 64;
        float xv = xr[d];
        xbr[d] = f2bf(xv);
        const float4* wr = (const float4*)(wg + (size_t)d * 8);
        float4 w0 = wr[0], w1 = wr[1];
        acc[0] += xv * w0.x; acc[1] += xv * w0.y; acc[2] += xv * w0.z; acc[3] += xv * w0.w;
        acc[4] += xv * w1.x; acc[5] += xv * w1.y; acc[6] += xv * w1.z; acc[7] += xv * w1.w;
    }
    #pragma unroll
    for (int s = 1; s < 64; s <<= 1) {
        #pragma unroll
        for (int e = 0; e < 8; e++) acc[e] += __shfl_xor(acc[e], s, 64);
    }
    if (lane == 0) {
        float l[8];
        #pragma unroll
        for (int e = 0; e < 8; e++) l[e] = acc[e] + bg[e];
        int i0 = 0;
        #pragma unroll
        for (int e = 1; e < 8; e++) if (l[e] > l[i0]) i0 = e;
        int i1 = (i0 == 0) ? 1 : 0;
        #pragma unroll
        for (int e = 0; e < 8; e++) if (e != i0 && l[e] > l[i1]) i1 = e;
        float z  = expf(l[i1] - l[i0]);          // <= 1
        float p0 = 1.0f / (1.0f + z);
        float p1 = z / (1.0f + z);
        float ent = -(p0 * logf(fmaxf(p0, 1e-8f)) + p1 * logf(fmaxf(p1, 1e-8f)));
        ents[wave] = ent;
        tk_e[t * 2 + 0] = i0; tk_g[t * 2 + 0] = p0;
        tk_e[t * 2 + 1] = i1; tk_g[t * 2 + 1] = p1;
    }
    __syncthreads();
    if (threadIdx.x == 0)
        ent_part[blockIdx.x] = ents[0] + ents[1] + ents[2] + ents[3];
}

// ------- routing: count + padded offsets + scatter + entropy reduce -------
__global__ __launch_bounds__(1024) void route_kernel(
    const int* __restrict__ tk_e, const float* __restrict__ tk_g,
    int* __restrict__ off, int* __restrict__ slot_token,
    float* __restrict__ slot_gate, int* __restrict__ slot_of,
    const float* __restrict__ ent_part, float* __restrict__ ent_out)
{
    __shared__ int wt[16][8];     // per-wave totals
    __shared__ int wx[16][8];     // per-wave exclusive prefix
    __shared__ int base[9];       // padded offsets
    __shared__ int tot[8];        // true counts
    __shared__ float es[16];

    int tid = threadIdx.x, wid = tid >> 6, lane = tid & 63;
    int i0 = tid * 8;
    int ev[8];
    *(int4*)&ev[0] = *(const int4*)&tk_e[i0];
    *(int4*)&ev[4] = *(const int4*)&tk_e[i0 + 4];

    // entropy reduction folded in (ent_part has exactly 1024 entries)
    float s = ent_part[tid];
    #pragma unroll
    for (int d = 1; d < 64; d <<= 1) s += __shfl_xor(s, d, 64);
    if (lane == 0) es[wid] = s;

    unsigned own[4] = {0u, 0u, 0u, 0u};
    #pragma unroll
    for (int j = 0; j < 8; j++) {
        int e = ev[j];
        int reg = ((e < 4) ? 0 : 2) + (e & 1);
        own[reg] += 1u << (((e >> 1) & 1) * 16);
    }
    unsigned inc[4] = {own[0], own[1], own[2], own[3]};
    #pragma unroll
    for (int d = 1; d < 64; d <<= 1) {
        #pragma unroll
        for (int k = 0; k < 4; k++) {
            unsigned t = __shfl_up(inc[k], d, 64);
            if (lane >= d) inc[k] += t;
        }
    }
    if (lane == 63) {
        #pragma unroll
        for (int e = 0; e < 8; e++) {
            int reg = ((e < 4) ? 0 : 2) + (e & 1);
            wt[wid][e] = (inc[reg] >> (((e >> 1) & 1) * 16)) & 0xFFFF;
        }
    }
    __syncthreads();
    if (tid == 0) {
        int o = 0;
        for (int e = 0; e < 8; e++) {
            int run = 0;
            for (int w = 0; w < 16; w++) { wx[w][e] = run; run += wt[w][e]; }
            tot[e] = run;
            base[e] = o;
            off[e] = o;
            o += (run + 127) & ~127;
        }
        base[8] = o;
        off[8] = o;
        float se = 0.f;
        for (int w = 0; w < 16; w++) se += es[w];
        *ent_out = se * (1.0f / T_TOK);
    }
    __syncthreads();

    #pragma unroll
    for (int e = 0; e < 8; e++) {
        int p0 = base[e] + tot[e], p1 = base[e + 1];
        for (int i = p0 + tid; i < p1; i += 1024) slot_token[i] = -1;
    }

    unsigned run[4] = {0u, 0u, 0u, 0u};
    #pragma unroll
    for (int j = 0; j < 8; j++) {
        int e = ev[j];
        int reg = ((e < 4) ? 0 : 2) + (e & 1);
        int sh = ((e >> 1) & 1) * 16;
        int lx = (int)(((inc[reg] - own[reg]) >> sh) & 0xFFFF);
        int lr = (int)((run[reg] >> sh) & 0xFFFF);
        int slot = base[e] + wx[wid][e] + lx + lr;
        run[reg] += 1u << sh;
        int i = i0 + j;
        slot_token[slot] = i >> 1;
        slot_gate[slot] = tk_g[i];
        slot_of[i] = slot;
    }
}

// ---------------- GEMM1: Hb = relu(gather(x) @ w1t[e]^T + b1[e]) ----------------
// BK=32 (16 KB LDS). Swizzle: LDS[row][c] = G[row][c ^ ((row>>1)&3)], c = 8-short chunk.
__global__ __launch_bounds__(256) void gemm1_kernel(
    const unsigned short* __restrict__ xb, const unsigned short* __restrict__ w1t,
    const float* __restrict__ b1g, const int* __restrict__ off,
    const int* __restrict__ slot_token, unsigned short* __restrict__ Hb)
{
    __shared__ __align__(16) unsigned short As[128 * 32];
    __shared__ __align__(16) unsigned short Bs[128 * 32];

    int s0 = blockIdx.x * 128;
    if (s0 >= off[E_EXP]) return;
    int e = 0;
    while (s0 >= off[e + 1]) e++;
    int n0 = blockIdx.y * 128;

    int tid = threadIdx.x;
    int wave = tid >> 6, lane = tid & 63;
    int lrow = lane & 15, quad = lane >> 4;
    int srow = lane >> 2;                       // 0..15: row within 16-row chunk
    int scol = ((lane & 3) ^ ((srow >> 1) & 3)) * 8;   // swizzled source chunk

    int r0 = 16 * wave + srow, r1 = r0 + 64;
    int t0 = slot_token[s0 + r0]; if (t0 < 0) t0 = 0;
    int t1 = slot_token[s0 + r1]; if (t1 < 0) t1 = 0;
    const unsigned short* wb = w1t + (size_t)e * H_DIM * D_DIM;
    const unsigned short* a0 = xb + (size_t)t0 * D_DIM + scol;
    const unsigned short* a1 = xb + (size_t)t1 * D_DIM + scol;
    const unsigned short* bp0 = wb + (size_t)(n0 + r0) * D_DIM + scol;
    const unsigned short* bp1 = wb + (size_t)(n0 + r1) * D_DIM + scol;

    unsigned short* lA0 = As + (16 * wave) * 32;
    unsigned short* lA1 = As + (64 + 16 * wave) * 32;
    unsigned short* lB0 = Bs + (16 * wave) * 32;
    unsigned short* lB1 = Bs + (64 + 16 * wave) * 32;

    f32x4 acc[4][4];
    #pragma unroll
    for (int mi = 0; mi < 4; mi++)
        #pragma unroll
        for (int ni = 0; ni < 4; ni++) acc[mi][ni] = (f32x4){0.f, 0.f, 0.f, 0.f};

    int wr = (wave >> 1) * 64, wc = (wave & 1) * 64;
    int g = (quad ^ ((lrow >> 1) & 3)) * 8;     // unswizzled fragment chunk

    for (int k0 = 0; k0 < D_DIM; k0 += 32) {
        __syncthreads();
        GLD_LDS16(a0 + k0, lA0);
        GLD_LDS16(a1 + k0, lA1);
        GLD_LDS16(bp0 + k0, lB0);
        GLD_LDS16(bp1 + k0, lB1);
        __syncthreads();
        bf16x8 af[4], bfr[4];
        #pragma unroll
        for (int i = 0; i < 4; i++) {
            af[i]  = *(const bf16x8*)&As[(wr + i * 16 + lrow) * 32 + g];
            bfr[i] = *(const bf16x8*)&Bs[(wc + i * 16 + lrow) * 32 + g];
        }
        #pragma unroll
        for (int mi = 0; mi < 4; mi++)
            #pragma unroll
            for (int ni = 0; ni < 4; ni++)
                acc[mi][ni] = __builtin_amdgcn_mfma_f32_16x16x32_bf16(
                    af[mi], bfr[ni], acc[mi][ni], 0, 0, 0);
    }

    // epilogue: LDS repack -> coalesced 16B stores. Each wave uses its own 1KB region.
    float bv[4];
    #pragma unroll
    for (int ni = 0; ni < 4; ni++) bv[ni] = b1g[e * H_DIM + n0 + wc + ni * 16 + lrow];
    unsigned short* w = As + wave * 1024;       // 16 rows x 64 cols
    __syncthreads();                            // all waves done reading K-loop LDS
    #pragma unroll
    for (int mi = 0; mi < 4; mi++) {
        #pragma unroll
        for (int ni = 0; ni < 4; ni++)
            #pragma unroll
            for (int r = 0; r < 4; r++)
                w[(quad * 4 + r) * 64 + ni * 16 + lrow] =
                    f2bf(fmaxf(acc[mi][ni][r] + bv[ni], 0.0f));
        // intra-wave LDS dependency only: no barrier needed
        int rd = lane >> 3, cc = (lane & 7) * 8;
        bf16x8 v0 = *(const bf16x8*)&w[rd * 64 + cc];
        bf16x8 v1 = *(const bf16x8*)&w[(8 + rd) * 64 + cc];
        size_t rowg = (size_t)(s0 + wr + mi * 16 + rd) * H_DIM + n0 + wc + cc;
        *(bf16x8*)&Hb[rowg] = v0;
        *(bf16x8*)&Hb[rowg + 8 * H_DIM] = v1;
    }
}

// ---------------- GEMM2: Yb = Hb @ w2t[e]^T + b2[e] (bf16 out) ----------------
__global__ __launch_bounds__(256) void gemm2_kernel(
    const unsigned short* __restrict__ Hb, const unsigned short* __restrict__ w2t,
    const float* __restrict__ b2g, const int* __restrict__ off,
    unsigned short* __restrict__ Yb)
{
    __shared__ __align__(16) unsigned short As[128 * 32];
    __shared__ __align__(16) unsigned short Bs[128 * 32];

    int s0 = blockIdx.x * 128;
    if (s0 >= off[E_EXP]) return;
    int e = 0;
    while (s0 >= off[e + 1]) e++;
    int n0 = blockIdx.y * 128;

    int tid = threadIdx.x;
    int wave = tid >> 6, lane = tid & 63;
    int lrow = lane & 15, quad = lane >> 4;
    int srow = lane >> 2;
    int scol = ((lane & 3) ^ ((srow >> 1) & 3)) * 8;

    int r0 = 16 * wave + srow, r1 = r0 + 64;
    const unsigned short* wb = w2t + (size_t)e * D_DIM * H_DIM;
    const unsigned short* a0 = Hb + (size_t)(s0 + r0) * H_DIM + scol;
    const unsigned short* a1 = Hb + (size_t)(s0 + r1) * H_DIM + scol;
    const unsigned short* bp0 = wb + (size_t)(n0 + r0) * H_DIM + scol;
    const unsigned short* bp1 = wb + (size_t)(n0 + r1) * H_DIM + scol;

    unsigned short* lA0 = As + (16 * wave) * 32;
    unsigned short* lA1 = As + (64 + 16 * wave) * 32;
    unsigned short* lB0 = Bs + (16 * wave) * 32;
    unsigned short* lB1 = Bs + (64 + 16 * wave) * 32;

    f32x4 acc[4][4];
    #pragma unroll
    for (int mi = 0; mi < 4; mi++)
        #pragma unroll
        for (int ni = 0; ni < 4; ni++) acc[mi][ni] = (f32x4){0.f, 0.f, 0.f, 0.f};

    int wr = (wave >> 1) * 64, wc = (wave & 1) * 64;
    int g = (quad ^ ((lrow >> 1) & 3)) * 8;

    for (int k0 = 0; k0 < H_DIM; k0 += 32) {
        __syncthreads();
        GLD_LDS16(a0 + k0, lA0);
        GLD_LDS16(a1 + k0, lA1);
        GLD_LDS16(bp0 + k0, lB0);
        GLD_LDS16(bp1 + k0, lB1);
        __syncthreads();
        bf16x8 af[4], bfr[4];
        #pragma unroll
        for (int i = 0; i < 4; i++) {
            af[i]  = *(const bf16x8*)&As[(wr + i * 16 + lrow) * 32 + g];
            bfr[i] = *(const bf16x8*)&Bs[(wc + i * 16 + lrow) * 32 + g];
        }
        #pragma unroll
        for (int mi = 0; mi < 4; mi++)
            #pragma unroll
            for (int ni = 0; ni < 4; ni++)
                acc[mi][ni] = __builtin_amdgcn_mfma_f32_16x16x32_bf16(
                    af[mi], bfr[ni], acc[mi][ni], 0, 0, 0);
    }

    float bv[4];
    #pragma unroll
    for (int ni = 0; ni < 4; ni++) bv[ni] = b2g[e * D_DIM + n0 + wc + ni * 16 + lrow];
    unsigned short* w = As + wave * 1024;
    __syncthreads();
    #pragma unroll
    for (int mi = 0; mi < 4; mi++) {
        #pragma unroll
        for (int ni = 0; ni < 4; ni++)
            #pragma unroll
            for (int r = 0; r < 4; r++)
                w[(quad * 4 + r) * 64 + ni * 16 + lrow] = f2bf(acc[mi][ni][r] + bv[ni]);
        int rd = lane >> 3, cc = (lane & 7) * 8;
        bf16x8 v0 = *(const bf16x8*)&w[rd * 64 + cc];
        bf16x8 v1 = *(const bf16x8*)&w[(8 + rd) * 64 + cc];
        size_t rowg = (size_t)(s0 + wr + mi * 16 + rd) * D_DIM + n0 + wc + cc;
        *(bf16x8*)&Yb[rowg] = v0;
        *(bf16x8*)&Yb[rowg + 8 * D_DIM] = v1;
    }
}

// ---------------- combine: out[t] = g0*Y[slot0] + g1*Y[slot1] ----------------
__global__ __launch_bounds__(256) void combine_kernel(
    const unsigned short* __restrict__ Yb, const int* __restrict__ slot_of,
    const float* __restrict__ tk_g, float* __restrict__ out)
{
    int t = blockIdx.x * 2 + (threadIdx.x >> 7);
    int j = threadIdx.x & 127;                 // 8 elements per thread
    int sA = slot_of[t * 2], sB = slot_of[t * 2 + 1];
    float gA = tk_g[t * 2], gB = tk_g[t * 2 + 1];
    uint4 va = *(const uint4*)(Yb + (size_t)sA * D_DIM + j * 8);
    uint4 vb = *(const uint4*)(Yb + (size_t)sB * D_DIM + j * 8);
    const unsigned int* pa = (const unsigned int*)&va;
    const unsigned int* pb = (const unsigned int*)&vb;
    float o[8];
    #pragma unroll
    for (int i = 0; i < 4; i++) {
        float a_lo = __uint_as_float(pa[i] << 16);
        float a_hi = __uint_as_float(pa[i] & 0xffff0000u);
        float b_lo = __uint_as_float(pb[i] << 16);
        float b_hi = __uint_as_float(pb[i] & 0xffff0000u);
        o[i * 2 + 0] = gA * a_lo + gB * b_lo;
        o[i * 2 + 1] = gA * a_hi + gB * b_hi;
    }
    float* op = out + (size_t)t * D_DIM + j * 8;
    ((float4*)op)[0] = make_float4(o[0], o[1], o[2], o[3]);
    ((float4*)op)[1] = make_float4(o[4], o[5], o[6], o[7]);
}

extern "C" void kernel_launch(void* const* d_in, const int* in_sizes, int n_in,
                              void* d_out, int out_size, void* d_ws, size_t ws_size,
                              hipStream_t stream)
{
    const float* xf = (const float*)d_in[0];
    const float* wg = (const float*)d_in[1];
    const float* bg = (const float*)d_in[2];
    const float* w1 = (const float*)d_in[3];
    const float* b1 = (const float*)d_in[4];
    const float* w2 = (const float*)d_in[5];
    const float* b2 = (const float*)d_in[6];
    float* out = (float*)d_out;

    char* p = (char*)d_ws;
    int* off    = (int*)p;                              // 16 (9 used)
    int* tk_e   = off + 16;                             // 8192
    float* tk_g = (float*)(tk_e + T_TOK * 2);           // 8192
    int* slot_token = (int*)(tk_g + T_TOK * 2);         // 9216
    float* slot_gate = (float*)(slot_token + CAP);      // 9216
    int* slot_of = (int*)(slot_gate + CAP);             // 8192
    float* ent_part = (float*)(slot_of + T_TOK * 2);    // 1024
    size_t ofs = ((size_t)((char*)(ent_part + T_TOK / 4) - p) + 255) & ~(size_t)255;
    unsigned short* xb  = (unsigned short*)(p + ofs); ofs += (size_t)T_TOK * D_DIM * 2;
    unsigned short* w1t = (unsigned short*)(p + ofs); ofs += (size_t)E_EXP * D_DIM * H_DIM * 2;
    unsigned short* w2t = (unsigned short*)(p + ofs); ofs += (size_t)E_EXP * H_DIM * D_DIM * 2;
    unsigned short* Hb  = (unsigned short*)(p + ofs); ofs += (size_t)CAP * H_DIM * 2;
    unsigned short* Yb  = w1t;   // alias: w1t is dead after gemm1

    gating_kernel<<<T_TOK / 4, 256, 0, stream>>>(xf, wg, bg, xb, tk_e, tk_g, ent_part);
    route_kernel<<<1, 1024, 0, stream>>>(tk_e, tk_g, off, slot_token, slot_gate, slot_of,
                                         ent_part, out + (size_t)T_TOK * D_DIM);
    // w1 (E, D, H) -> w1t (E, H, D)
    tcvt_kernel<<<dim3(H_DIM / 64, D_DIM / 64, E_EXP), 256, 0, stream>>>(w1, w1t, D_DIM, H_DIM);
    // w2 (E, H, D) -> w2t (E, D, H)
    tcvt_kernel<<<dim3(D_DIM / 64, H_DIM / 64, E_EXP), 256, 0, stream>>>(w2, w2t, H_DIM, D_DIM);
    gemm1_kernel<<<dim3(TILES_M, H_DIM / 128), 256, 0, stream>>>(xb, w1t, b1, off,
                                                                 slot_token, Hb);
    gemm2_kernel<<<dim3(TILES_M, D_DIM / 128), 256, 0, stream>>>(Hb, w2t, b2, off, Yb);
    combine_kernel<<<T_TOK / 2, 256, 0, stream>>>(Yb, slot_of, tk_g, out);
}